// Round 9
// baseline (94.658 us; speedup 1.0000x reference)
//
#include <hip/hip_runtime.h>
#include <hip/hip_fp16.h>

// ContinuousFilterConv on MI355X (gfx950), round 9.
// filtered[e,i] = sum_{u,j} h[e,u] * tm[e,j] * W2ext[u, i*128+j]
// GEMM C[8192x128] = A[8192x16512] @ B[16512x128], f16 MFMA, A generated on
// the fly (outer product h x tm). K split over 8 u-chunks, grid 512,
// round-8 barrier-free reg-dbuf loop (distance-2) kept verbatim.
// Round 9: (a) scatter-add via packed global_atomic_pk_add_f16 into an f16
// message buffer (atomic ops 8.4M -> 4.2M), (b) k3 = f16 msg -> silu -> f32,
// (c) k0 W2-conversion rewritten with coalesced row reads through LDS.

typedef _Float16 f16;
typedef __attribute__((ext_vector_type(8))) f16 f16x8;
typedef __attribute__((ext_vector_type(4))) float f32x4;
typedef __attribute__((ext_vector_type(4))) unsigned int u32x4;

#define NEDGE 8192
#define NNODE 20000
#define NG    50
#define KSTEPS 516                       // 129 u-rows * 128 j / 32
#define W2C_BYTES (KSTEPS * 8192)        // [step][nt8][lane64][8] f16
#define HT_BYTES (64 * 132 * 128 * 2)    // [eb][u(132, 128=ones)][el(128)] f16
#define TM_BYTES (NEDGE * 128 * 2)       // [e][j^swz] f16 (mask folded, pre-swizzled)
#define MSGH_BYTES (NNODE * 128 * 2)     // f16 message accumulator

// k2 LDS map (bytes) — prologue staging only
#define LDS_H   0                        // 20 rows x 256 B = 5120
#define LDS_TM  5120                     // 128 x 256 B (swizzled) = 32768
#define LDS_TOT 37888

static __device__ __forceinline__ float fsilu(float x) { return x / (1.0f + __expf(-x)); }

static __device__ __forceinline__ void gll16(const void* g, void* l) {
  __builtin_amdgcn_global_load_lds(
      (const __attribute__((address_space(1))) unsigned int*)g,
      (__attribute__((address_space(3))) unsigned int*)l, 16, 0, 0);
}

// ---- k01: fused {W2->w2c coalesced convert | per-edge h,tm | zero msgh} ----
// blocks [0,129): one W2 row (or b2) each, staged via LDS, coalesced both ways
// blocks [129,641): k1 per-edge h/tm
// blocks [641,954): zero the f16 message buffer
__global__ __launch_bounds__(256) void k01(const float* __restrict__ W2,
                                           const float* __restrict__ b2,
                                           const float* __restrict__ NF,
                                           const int*   __restrict__ EI,
                                           const float* __restrict__ DI,
                                           const float* __restrict__ W1,
                                           const float* __restrict__ B1,
                                           const float* __restrict__ WT,
                                           f16* __restrict__ w2c,
                                           f16* __restrict__ ht2,
                                           f16* __restrict__ tmo,
                                           __half* __restrict__ msgh) {
  __shared__ union {
    f16 row[16384];                                        // k0 path: 32 KB
    struct {
      float df[16][NG]; float mask[16]; float src[16][128];
      float tt[16][132]; float ht[16][132];
    } k1;
  } sm;
  const int bid = blockIdx.x, tid = threadIdx.x;

  if (bid < 129) {
    // ---- k0: convert one row u (u=128 -> b2) to frag-linear f16 ----
    const int u = bid;
    const float* src = (u < 128) ? (W2 + (size_t)u * 16384) : b2;
#pragma unroll
    for (int it = 0; it < 16; ++it) {
      int idx = it * 1024 + tid * 4;                       // coalesced f32x4
      f32x4 v = *(const f32x4*)(src + idx);
#pragma unroll
      for (int r = 0; r < 4; ++r) sm.row[idx + r] = (f16)v[r];
    }
    __syncthreads();
#pragma unroll
    for (int q = 0; q < 8; ++q) {
      int fi = q * 256 + tid;                              // 2048 frags per row
      int lane = fi & 63, nt = (fi >> 6) & 7, s = fi >> 9; // s in 0..3
      int i = nt * 16 + (lane & 15);
      int j = s * 32 + (lane >> 4) * 8;
      u32x4 frag = *(const u32x4*)&sm.row[i * 128 + j];
      *((u32x4*)w2c + (size_t)(u * 4 + s) * 512 + nt * 64 + lane) = frag;
    }
    return;
  }
  if (bid < 641) {
    // ---- k1: per-edge h (unmasked) and tm = mask * (src@Wt) ----
    int et = bid - 129, e0 = et * 16;
    for (int idx = tid; idx < 16 * NG; idx += 256) {
      int e = idx / NG, g = idx - e * NG;
      float d = DI[e0 + e];
      float x = d - (float)g * (30.0f / 49.0f);
      sm.k1.df[e][g] = __expf(-10.0f * x * x);
    }
    if (tid < 16) sm.k1.mask[tid] = (DI[e0 + tid] <= 8.0f) ? 1.0f : 0.0f;
    for (int idx = tid; idx < 16 * 128; idx += 256) {
      int e = idx >> 7, u = idx & 127;
      sm.k1.src[e][u] = NF[(size_t)EI[e0 + e] * 128 + u];
    }
    __syncthreads();

    int j = tid & 127, es = tid >> 7;
    for (int e = es * 8; e < es * 8 + 8; ++e) {
      float acc = B1[j];
      for (int g = 0; g < NG; ++g) acc += sm.k1.df[e][g] * W1[g * 128 + j];
      sm.k1.ht[e][j] = fsilu(acc);
    }
    {
      float acc[8] = {0.f,0.f,0.f,0.f,0.f,0.f,0.f,0.f};
      for (int u = 0; u < 128; ++u) {
        float wv = WT[u * 128 + j];
#pragma unroll
        for (int e8 = 0; e8 < 8; ++e8) acc[e8] += sm.k1.src[es * 8 + e8][u] * wv;
      }
#pragma unroll
      for (int e8 = 0; e8 < 8; ++e8) sm.k1.tt[es * 8 + e8][j] = acc[e8];
    }
    __syncthreads();

    int eb = et >> 3, el0 = (et & 7) * 16;
    {
      int u = tid >> 1, hf = tid & 1;
      union { f16 s[8]; u32x4 v; } pk;
#pragma unroll
      for (int k = 0; k < 8; ++k) pk.s[k] = (f16)sm.k1.ht[hf * 8 + k][u];
      *(u32x4*)(ht2 + ((size_t)eb * 132 + u) * 128 + el0 + hf * 8) = pk.v;
    }
    if (tid < 16) ht2[((size_t)eb * 132 + 128) * 128 + el0 + tid] = (f16)1.0f; // ones (b2)
    {
      int e = tid >> 4, cc = tid & 15;
      float m = sm.k1.mask[e];
      union { f16 s[8]; u32x4 v; } pk;
#pragma unroll
      for (int k = 0; k < 8; ++k) pk.s[k] = (f16)(m * sm.k1.tt[e][cc * 8 + k]);
      int col = (cc * 16) ^ ((e & 7) << 4);
      *(u32x4*)((char*)tmo + (size_t)(e0 + e) * 256 + col) = pk.v;
    }
    return;
  }
  // ---- zero msgh (320,000 u32x4 chunks) ----
  {
    int base = (bid - 641) * 1024;
    u32x4 z = {0u, 0u, 0u, 0u};
#pragma unroll
    for (int k = 0; k < 4; ++k) {
      int i4 = base + k * 256 + tid;
      if (i4 < (MSGH_BYTES / 16)) ((u32x4*)msgh)[i4] = z;
    }
  }
}

// ---------------- k2: fused outer-product GEMM + packed-f16 scatter ---------
// grid 512: chunk c = bid&7 (16 u, c==7: 17 incl. b2 row), eb = bid>>3.
// Block: 4 waves 2x2 over 128e x 128i; wave = 64e x 64i; acc[4][4] f32x4.
// Main loop (round-8, unchanged): no barriers, no LDS; tm frags in VGPRs;
// B global->reg, 2 static buffers (parity jc&1), prefetch distance 2.
__global__ __launch_bounds__(256, 2) void k2_gemm(const f16* __restrict__ w2c,
                                                  const f16* __restrict__ ht2,
                                                  const f16* __restrict__ tm,
                                                  const int* __restrict__ EI,
                                                  __half* __restrict__ msgh) {
  __shared__ u32x4 smem_v[LDS_TOT / 16];
  char* smem = (char*)smem_v;

  const int bid = blockIdx.x;
  const int c   = bid & 7;
  const int eb  = bid >> 3;
  const int e0  = eb * 128;
  const int nu  = (c == 7) ? 17 : 16;
  const int tid = threadIdx.x, w = tid >> 6, lane = tid & 63;
  const int l15 = lane & 15, g4 = lane >> 4;
  const int wm = w >> 1, wn = w & 1;

  // ---- prologue staging (tm swizzled + h), one-time ----
  {
    const char* tsrc = (const char*)tm + (size_t)e0 * 256 + w * 8192;
#pragma unroll
    for (int q = 0; q < 8; ++q)
      gll16(tsrc + q * 1024 + lane * 16,
            smem + LDS_TM + w * 8192 + q * 1024 + lane * 16);
  }
  if (w == 0) {   // 20 h rows
    const char* hsrc = (const char*)ht2 + ((size_t)eb * 132 + c * 16) * 256;
#pragma unroll
    for (int q = 0; q < 5; ++q)
      gll16(hsrc + q * 1024 + lane * 16, smem + LDS_H + q * 1024 + lane * 16);
  }
  __syncthreads();

  // ---- tm A-frags: u-invariant -> load ALL into registers once ----
  f16x8 Tall[4][4];
  {
    const int tmrow = LDS_TM + (wm * 64 + l15) * 256;
    const int colsw = (l15 & 7) << 4;
#pragma unroll
    for (int rt = 0; rt < 4; ++rt)
#pragma unroll
      for (int jc = 0; jc < 4; ++jc)
        Tall[rt][jc] = *(const f16x8*)(smem + tmrow + rt * 4096 +
                                       ((jc * 64 + g4 * 16) ^ colsw));
  }
  const __half* hbase = (const __half*)(smem + LDS_H) + wm * 64 + l15;

  __half2 hc[4], hn[4];
#pragma unroll
  for (int rt = 0; rt < 4; ++rt) hc[rt] = __half2half2(hbase[rt * 16]);

  // ---- B stream: global->reg, 2 static buffers, distance-2 prefetch ----
  const char* bp = (const char*)w2c + (size_t)(c * 64) * 8192 + wn * 4096 + lane * 16;
  f16x8 B0[4], B1[4];
#pragma unroll
  for (int nt = 0; nt < 4; ++nt) B0[nt] = *(const f16x8*)(bp + nt * 1024);          // ph 0
#pragma unroll
  for (int nt = 0; nt < 4; ++nt) B1[nt] = *(const f16x8*)(bp + 8192 + nt * 1024);   // ph 1
  size_t off = 2 * 8192;                                // next prefetch target: ph 2

  f32x4 acc[4][4];
#pragma unroll
  for (int rt = 0; rt < 4; ++rt)
#pragma unroll
    for (int nt = 0; nt < 4; ++nt) acc[rt][nt] = (f32x4){0.f, 0.f, 0.f, 0.f};

  for (int u = 0; u < nu; ++u) {
#pragma unroll
    for (int jc = 0; jc < 4; ++jc) {
      if (jc == 1) {   // prefetch next u's h (rows < 20 staged; tail value unused)
#pragma unroll
        for (int rt = 0; rt < 4; ++rt)
          hn[rt] = __half2half2(hbase[(u + 1) * 128 + rt * 16]);
      }
      // A-gen from register-resident tm frags
      union uf { f16x8 v; __half2 h[4]; };
      uf a[4];
#pragma unroll
      for (int rt = 0; rt < 4; ++rt) {
        uf t; t.v = Tall[rt][jc];
#pragma unroll
        for (int q = 0; q < 4; ++q) a[rt].h[q] = __hmul2(t.h[q], hc[rt]);
      }
      // per-nt: 4 MFMAs consume B[jc&1][nt], then reload it with phase p+2
      // (tail prefetch overruns chunk but stays inside w2c: verified in-bounds)
      __builtin_amdgcn_s_setprio(1);
#pragma unroll
      for (int nt = 0; nt < 4; ++nt) {
        if ((jc & 1) == 0) {
#pragma unroll
          for (int rt = 0; rt < 4; ++rt)
            acc[rt][nt] = __builtin_amdgcn_mfma_f32_16x16x32_f16(a[rt].v, B0[nt], acc[rt][nt], 0, 0, 0);
          B0[nt] = *(const f16x8*)(bp + off + nt * 1024);
        } else {
#pragma unroll
          for (int rt = 0; rt < 4; ++rt)
            acc[rt][nt] = __builtin_amdgcn_mfma_f32_16x16x32_f16(a[rt].v, B1[nt], acc[rt][nt], 0, 0, 0);
          B1[nt] = *(const f16x8*)(bp + off + nt * 1024);
        }
      }
      __builtin_amdgcn_s_setprio(0);
      off += 8192;
    }
#pragma unroll
    for (int rt = 0; rt < 4; ++rt) hc[rt] = hn[rt];
  }

  // epilogue: packed-f16 scatter-add (2 i-values per atomic via lane pairing)
  const int* dst = EI + NEDGE;
#pragma unroll
  for (int rt = 0; rt < 4; ++rt) {
#pragma unroll
    for (int r = 0; r < 4; ++r) {
      int e = e0 + wm * 64 + rt * 16 + g4 * 4 + r;
      size_t rowb = (size_t)dst[e] * 128 + wn * 64;
#pragma unroll
      for (int nt = 0; nt < 4; ++nt) {
        float v  = acc[rt][nt][r];
        float pv = __shfl_xor(v, 1, 64);              // partner i+1 (odd l15)
        if ((l15 & 1) == 0) {
          __half2 h2;
          h2.x = __float2half_rn(v);
          h2.y = __float2half_rn(pv);
          unsigned int d = *(unsigned int*)&h2;
          unsigned long long addr =
              (unsigned long long)(msgh + rowb + nt * 16 + l15);
          asm volatile("global_atomic_pk_add_f16 %0, %1, off"
                       :: "v"(addr), "v"(d) : "memory");
        }
      }
    }
  }
}

// ---------------- k3: out = silu(msgh) (f16 -> f32) --------------------------
__global__ __launch_bounds__(256) void k3_silu(const __half* __restrict__ msgh,
                                               float* __restrict__ out, int n8) {
  int idx = blockIdx.x * 256 + threadIdx.x;
  if (idx >= n8) return;
  union { u32x4 v; __half h[8]; } r;
  r.v = *(const u32x4*)(msgh + (size_t)idx * 8);
  f32x4 o0, o1;
#pragma unroll
  for (int cc = 0; cc < 4; ++cc) {
    o0[cc] = fsilu(__half2float(r.h[cc]));
    o1[cc] = fsilu(__half2float(r.h[4 + cc]));
  }
  *(f32x4*)(out + (size_t)idx * 8)     = o0;
  *(f32x4*)(out + (size_t)idx * 8 + 4) = o1;
}

extern "C" void kernel_launch(void* const* d_in, const int* in_sizes, int n_in,
                              void* d_out, int out_size, void* d_ws, size_t ws_size,
                              hipStream_t stream) {
  const float* NF = (const float*)d_in[0];
  const int*   EI = (const int*)  d_in[1];
  const float* DI = (const float*)d_in[2];
  const float* W1 = (const float*)d_in[3];
  const float* B1 = (const float*)d_in[4];
  const float* W2 = (const float*)d_in[5];
  const float* B2 = (const float*)d_in[6];
  const float* WT = (const float*)d_in[7];
  float* out = (float*)d_out;

  f16*    w2c  = (f16*)d_ws;
  f16*    ht2  = (f16*)((char*)d_ws + W2C_BYTES);
  f16*    tmo  = (f16*)((char*)d_ws + W2C_BYTES + HT_BYTES);
  __half* msgh = (__half*)((char*)d_ws + W2C_BYTES + HT_BYTES + TM_BYTES);
  size_t needed = (size_t)W2C_BYTES + HT_BYTES + TM_BYTES + MSGH_BYTES;
  if (ws_size < needed) return;  // insufficient scratch: fail loudly

  k01    <<<dim3(954),  dim3(256), 0, stream>>>(W2, B2, NF, EI, DI, W1, B1, WT,
                                                w2c, ht2, tmo, msgh);
  k2_gemm<<<dim3(512),  dim3(256), 0, stream>>>(w2c, ht2, tmo, EI, msgh);
  k3_silu<<<dim3(1250), dim3(256), 0, stream>>>(msgh, out, NNODE * 128 / 8);
}

// Round 10
// 85.181 us; speedup vs baseline: 1.1113x; 1.1113x over previous
//
#include <hip/hip_runtime.h>
#include <hip/hip_fp16.h>

// ContinuousFilterConv on MI355X (gfx950), round 10.
// filtered[e,i] = sum_{u,j} h[e,u] * tm[e,j] * W2ext[u, i*128+j]
// GEMM C[8192x128] = A[8192x16512] @ B[16512x128], f16 MFMA, A generated on
// the fly (outer product h x tm). K split over 8 u-chunks, grid 512,
// round-8 barrier-free reg-dbuf loop (distance-2) kept VERBATIM.
// Round 10: k2 epilogue = plain f32 partial stores (no atomics); new k4 sums
// the 8 chunk-partials per edge and scatters with 1M f32 atomics (8x fewer).
// Fallback to the round-8 atomic epilogue if d_ws is too small.

typedef _Float16 f16;
typedef __attribute__((ext_vector_type(8))) f16 f16x8;
typedef __attribute__((ext_vector_type(4))) float f32x4;
typedef __attribute__((ext_vector_type(4))) unsigned int u32x4;

#define NEDGE 8192
#define NNODE 20000
#define NG    50
#define KSTEPS 516                       // 129 u-rows * 128 j / 32
#define W2C_BYTES (KSTEPS * 8192)        // [step][nt8][lane64][8] f16
#define HT_BYTES (64 * 132 * 128 * 2)    // [eb][u(132, 128=ones)][el(128)] f16
#define TM_BYTES (NEDGE * 128 * 2)       // [e][j^swz] f16 (mask folded, pre-swizzled)
#define FP_BYTES ((size_t)8 * NEDGE * 128 * 4)  // f32 partials [c][e][i] = 32 MB

// k2 LDS map (bytes) — prologue staging only
#define LDS_H   0                        // 20 rows x 256 B = 5120
#define LDS_TM  5120                     // 128 x 256 B (swizzled) = 32768
#define LDS_TOT 37888

static __device__ __forceinline__ float fsilu(float x) { return x / (1.0f + __expf(-x)); }

static __device__ __forceinline__ void gll16(const void* g, void* l) {
  __builtin_amdgcn_global_load_lds(
      (const __attribute__((address_space(1))) unsigned int*)g,
      (__attribute__((address_space(3))) unsigned int*)l, 16, 0, 0);
}

// ---- k01: fused {W2->w2c coalesced convert | per-edge h,tm | zero d_out} ---
// blocks [0,129): one W2 row (or b2) each, staged via LDS, coalesced both ways
// blocks [129,641): k1 per-edge h/tm
// blocks [641,1266): zero d_out
__global__ __launch_bounds__(256) void k01(const float* __restrict__ W2,
                                           const float* __restrict__ b2,
                                           const float* __restrict__ NF,
                                           const int*   __restrict__ EI,
                                           const float* __restrict__ DI,
                                           const float* __restrict__ W1,
                                           const float* __restrict__ B1,
                                           const float* __restrict__ WT,
                                           f16* __restrict__ w2c,
                                           f16* __restrict__ ht2,
                                           f16* __restrict__ tmo,
                                           float* __restrict__ out, int nz4) {
  __shared__ union {
    f16 row[16384];                                        // k0 path: 32 KB
    struct {
      float df[16][NG]; float mask[16]; float src[16][128];
      float tt[16][132]; float ht[16][132];
    } k1;
  } sm;
  const int bid = blockIdx.x, tid = threadIdx.x;

  if (bid < 129) {
    // ---- k0: convert one row u (u=128 -> b2) to frag-linear f16 ----
    const int u = bid;
    const float* src = (u < 128) ? (W2 + (size_t)u * 16384) : b2;
#pragma unroll
    for (int it = 0; it < 16; ++it) {
      int idx = it * 1024 + tid * 4;                       // coalesced f32x4
      f32x4 v = *(const f32x4*)(src + idx);
#pragma unroll
      for (int r = 0; r < 4; ++r) sm.row[idx + r] = (f16)v[r];
    }
    __syncthreads();
#pragma unroll
    for (int q = 0; q < 8; ++q) {
      int fi = q * 256 + tid;                              // 2048 frags per row
      int lane = fi & 63, nt = (fi >> 6) & 7, s = fi >> 9; // s in 0..3
      int i = nt * 16 + (lane & 15);
      int j = s * 32 + (lane >> 4) * 8;
      u32x4 frag = *(const u32x4*)&sm.row[i * 128 + j];
      *((u32x4*)w2c + (size_t)(u * 4 + s) * 512 + nt * 64 + lane) = frag;
    }
    return;
  }
  if (bid < 641) {
    // ---- k1: per-edge h (unmasked) and tm = mask * (src@Wt) ----
    int et = bid - 129, e0 = et * 16;
    for (int idx = tid; idx < 16 * NG; idx += 256) {
      int e = idx / NG, g = idx - e * NG;
      float d = DI[e0 + e];
      float x = d - (float)g * (30.0f / 49.0f);
      sm.k1.df[e][g] = __expf(-10.0f * x * x);
    }
    if (tid < 16) sm.k1.mask[tid] = (DI[e0 + tid] <= 8.0f) ? 1.0f : 0.0f;
    for (int idx = tid; idx < 16 * 128; idx += 256) {
      int e = idx >> 7, u = idx & 127;
      sm.k1.src[e][u] = NF[(size_t)EI[e0 + e] * 128 + u];
    }
    __syncthreads();

    int j = tid & 127, es = tid >> 7;
    for (int e = es * 8; e < es * 8 + 8; ++e) {
      float acc = B1[j];
      for (int g = 0; g < NG; ++g) acc += sm.k1.df[e][g] * W1[g * 128 + j];
      sm.k1.ht[e][j] = fsilu(acc);
    }
    {
      float acc[8] = {0.f,0.f,0.f,0.f,0.f,0.f,0.f,0.f};
      for (int u = 0; u < 128; ++u) {
        float wv = WT[u * 128 + j];
#pragma unroll
        for (int e8 = 0; e8 < 8; ++e8) acc[e8] += sm.k1.src[es * 8 + e8][u] * wv;
      }
#pragma unroll
      for (int e8 = 0; e8 < 8; ++e8) sm.k1.tt[es * 8 + e8][j] = acc[e8];
    }
    __syncthreads();

    int eb = et >> 3, el0 = (et & 7) * 16;
    {
      int u = tid >> 1, hf = tid & 1;
      union { f16 s[8]; u32x4 v; } pk;
#pragma unroll
      for (int k = 0; k < 8; ++k) pk.s[k] = (f16)sm.k1.ht[hf * 8 + k][u];
      *(u32x4*)(ht2 + ((size_t)eb * 132 + u) * 128 + el0 + hf * 8) = pk.v;
    }
    if (tid < 16) ht2[((size_t)eb * 132 + 128) * 128 + el0 + tid] = (f16)1.0f; // ones (b2)
    {
      int e = tid >> 4, cc = tid & 15;
      float m = sm.k1.mask[e];
      union { f16 s[8]; u32x4 v; } pk;
#pragma unroll
      for (int k = 0; k < 8; ++k) pk.s[k] = (f16)(m * sm.k1.tt[e][cc * 8 + k]);
      int col = (cc * 16) ^ ((e & 7) << 4);
      *(u32x4*)((char*)tmo + (size_t)(e0 + e) * 256 + col) = pk.v;
    }
    return;
  }
  // ---- zero d_out ----
  {
    int base = (bid - 641) * 1024;
    f32x4 z = {0.f, 0.f, 0.f, 0.f};
#pragma unroll
    for (int k = 0; k < 4; ++k) {
      int i4 = base + k * 256 + tid;
      if (i4 < nz4) ((f32x4*)out)[i4] = z;
    }
  }
}

// ---------------- k2: fused outer-product GEMM + partial store --------------
// grid 512: chunk c = bid&7 (16 u, c==7: 17 incl. b2 row), eb = bid>>3.
// Block: 4 waves 2x2 over 128e x 128i; wave = 64e x 64i; acc[4][4] f32x4.
// Main loop (round-8, unchanged): no barriers, no LDS; tm frags in VGPRs;
// B global->reg, 2 static buffers (parity jc&1), prefetch distance 2.
// MODE 0: plain f32 stores to fpart[c][e][i].  MODE 1: atomicAdd to msg.
template<int MODE>
__global__ __launch_bounds__(256, 2) void k2_gemm(const f16* __restrict__ w2c,
                                                  const f16* __restrict__ ht2,
                                                  const f16* __restrict__ tm,
                                                  const int* __restrict__ EI,
                                                  float* __restrict__ fpart,
                                                  float* __restrict__ msg) {
  __shared__ u32x4 smem_v[LDS_TOT / 16];
  char* smem = (char*)smem_v;

  const int bid = blockIdx.x;
  const int c   = bid & 7;
  const int eb  = bid >> 3;
  const int e0  = eb * 128;
  const int nu  = (c == 7) ? 17 : 16;
  const int tid = threadIdx.x, w = tid >> 6, lane = tid & 63;
  const int l15 = lane & 15, g4 = lane >> 4;
  const int wm = w >> 1, wn = w & 1;

  // ---- prologue staging (tm swizzled + h), one-time ----
  {
    const char* tsrc = (const char*)tm + (size_t)e0 * 256 + w * 8192;
#pragma unroll
    for (int q = 0; q < 8; ++q)
      gll16(tsrc + q * 1024 + lane * 16,
            smem + LDS_TM + w * 8192 + q * 1024 + lane * 16);
  }
  if (w == 0) {   // 20 h rows
    const char* hsrc = (const char*)ht2 + ((size_t)eb * 132 + c * 16) * 256;
#pragma unroll
    for (int q = 0; q < 5; ++q)
      gll16(hsrc + q * 1024 + lane * 16, smem + LDS_H + q * 1024 + lane * 16);
  }
  __syncthreads();

  // ---- tm A-frags: u-invariant -> load ALL into registers once ----
  f16x8 Tall[4][4];
  {
    const int tmrow = LDS_TM + (wm * 64 + l15) * 256;
    const int colsw = (l15 & 7) << 4;
#pragma unroll
    for (int rt = 0; rt < 4; ++rt)
#pragma unroll
      for (int jc = 0; jc < 4; ++jc)
        Tall[rt][jc] = *(const f16x8*)(smem + tmrow + rt * 4096 +
                                       ((jc * 64 + g4 * 16) ^ colsw));
  }
  const __half* hbase = (const __half*)(smem + LDS_H) + wm * 64 + l15;

  __half2 hc[4], hn[4];
#pragma unroll
  for (int rt = 0; rt < 4; ++rt) hc[rt] = __half2half2(hbase[rt * 16]);

  // ---- B stream: global->reg, 2 static buffers, distance-2 prefetch ----
  const char* bp = (const char*)w2c + (size_t)(c * 64) * 8192 + wn * 4096 + lane * 16;
  f16x8 B0[4], B1[4];
#pragma unroll
  for (int nt = 0; nt < 4; ++nt) B0[nt] = *(const f16x8*)(bp + nt * 1024);          // ph 0
#pragma unroll
  for (int nt = 0; nt < 4; ++nt) B1[nt] = *(const f16x8*)(bp + 8192 + nt * 1024);   // ph 1
  size_t off = 2 * 8192;                                // next prefetch target: ph 2

  f32x4 acc[4][4];
#pragma unroll
  for (int rt = 0; rt < 4; ++rt)
#pragma unroll
    for (int nt = 0; nt < 4; ++nt) acc[rt][nt] = (f32x4){0.f, 0.f, 0.f, 0.f};

  for (int u = 0; u < nu; ++u) {
#pragma unroll
    for (int jc = 0; jc < 4; ++jc) {
      if (jc == 1) {   // prefetch next u's h (rows < 20 staged; tail value unused)
#pragma unroll
        for (int rt = 0; rt < 4; ++rt)
          hn[rt] = __half2half2(hbase[(u + 1) * 128 + rt * 16]);
      }
      // A-gen from register-resident tm frags
      union uf { f16x8 v; __half2 h[4]; };
      uf a[4];
#pragma unroll
      for (int rt = 0; rt < 4; ++rt) {
        uf t; t.v = Tall[rt][jc];
#pragma unroll
        for (int q = 0; q < 4; ++q) a[rt].h[q] = __hmul2(t.h[q], hc[rt]);
      }
      // per-nt: 4 MFMAs consume B[jc&1][nt], then reload it with phase p+2
      // (tail prefetch overruns chunk but stays inside w2c: in-bounds)
      __builtin_amdgcn_s_setprio(1);
#pragma unroll
      for (int nt = 0; nt < 4; ++nt) {
        if ((jc & 1) == 0) {
#pragma unroll
          for (int rt = 0; rt < 4; ++rt)
            acc[rt][nt] = __builtin_amdgcn_mfma_f32_16x16x32_f16(a[rt].v, B0[nt], acc[rt][nt], 0, 0, 0);
          B0[nt] = *(const f16x8*)(bp + off + nt * 1024);
        } else {
#pragma unroll
          for (int rt = 0; rt < 4; ++rt)
            acc[rt][nt] = __builtin_amdgcn_mfma_f32_16x16x32_f16(a[rt].v, B1[nt], acc[rt][nt], 0, 0, 0);
          B1[nt] = *(const f16x8*)(bp + off + nt * 1024);
        }
      }
      __builtin_amdgcn_s_setprio(0);
      off += 8192;
    }
#pragma unroll
    for (int rt = 0; rt < 4; ++rt) hc[rt] = hn[rt];
  }

  if (MODE == 0) {
    // epilogue: plain coalesced f32 partial stores (no atomics)
#pragma unroll
    for (int rt = 0; rt < 4; ++rt) {
#pragma unroll
      for (int r = 0; r < 4; ++r) {
        int e = e0 + wm * 64 + rt * 16 + g4 * 4 + r;
        float* prow = fpart + ((size_t)c * NEDGE + e) * 128 + wn * 64 + l15;
#pragma unroll
        for (int nt = 0; nt < 4; ++nt)
          prow[nt * 16] = acc[rt][nt][r];
      }
    }
  } else {
    // fallback epilogue: scatter-add partials directly (round-8 path)
    const int* dst = EI + NEDGE;
#pragma unroll
    for (int rt = 0; rt < 4; ++rt) {
#pragma unroll
      for (int r = 0; r < 4; ++r) {
        int e = e0 + wm * 64 + rt * 16 + g4 * 4 + r;
        float* row = msg + (size_t)dst[e] * 128 + wn * 64 + l15;
#pragma unroll
        for (int nt = 0; nt < 4; ++nt)
          atomicAdd(row + nt * 16, acc[rt][nt][r]);
      }
    }
  }
}

// -------- k4: sum 8 chunk-partials per edge, scatter-add to nodes -----------
__global__ __launch_bounds__(256) void k4_reduce(const float* __restrict__ fp,
                                                 const int* __restrict__ EI,
                                                 float* __restrict__ out) {
  int gid = blockIdx.x * 256 + threadIdx.x;     // 262144 = 8192 e * 32
  int e  = gid >> 5;
  int i0 = (gid & 31) << 2;
  f32x4 s = {0.f, 0.f, 0.f, 0.f};
#pragma unroll
  for (int cc = 0; cc < 8; ++cc) {
    f32x4 v = *(const f32x4*)(fp + ((size_t)cc * NEDGE + e) * 128 + i0);
    s[0] += v[0]; s[1] += v[1]; s[2] += v[2]; s[3] += v[3];
  }
  float* row = out + (size_t)EI[NEDGE + e] * 128 + i0;
  atomicAdd(row + 0, s[0]);
  atomicAdd(row + 1, s[1]);
  atomicAdd(row + 2, s[2]);
  atomicAdd(row + 3, s[3]);
}

// ---------------- k3: out = silu(out) ----------------------------------------
__global__ __launch_bounds__(256) void k3_silu(float* __restrict__ out, int n4) {
  int idx = blockIdx.x * 256 + threadIdx.x;
  int stride = gridDim.x * 256;
  f32x4* p = (f32x4*)out;
  for (; idx < n4; idx += stride) {
    f32x4 v = p[idx];
#pragma unroll
    for (int cc = 0; cc < 4; ++cc) v[cc] = fsilu(v[cc]);
    p[idx] = v;
  }
}

extern "C" void kernel_launch(void* const* d_in, const int* in_sizes, int n_in,
                              void* d_out, int out_size, void* d_ws, size_t ws_size,
                              hipStream_t stream) {
  const float* NF = (const float*)d_in[0];
  const int*   EI = (const int*)  d_in[1];
  const float* DI = (const float*)d_in[2];
  const float* W1 = (const float*)d_in[3];
  const float* B1 = (const float*)d_in[4];
  const float* W2 = (const float*)d_in[5];
  const float* B2 = (const float*)d_in[6];
  const float* WT = (const float*)d_in[7];
  float* out = (float*)d_out;

  f16*   w2c = (f16*)d_ws;
  f16*   ht2 = (f16*)((char*)d_ws + W2C_BYTES);
  f16*   tmo = (f16*)((char*)d_ws + W2C_BYTES + HT_BYTES);
  float* fp  = (float*)((char*)d_ws + W2C_BYTES + HT_BYTES + TM_BYTES);
  size_t need_min  = (size_t)W2C_BYTES + HT_BYTES + TM_BYTES;
  size_t need_fast = need_min + FP_BYTES;
  if (ws_size < need_min) return;  // insufficient scratch: fail loudly
  const bool fast = (ws_size >= need_fast);

  int nz4 = out_size / 4;
  k01<<<dim3(1266), dim3(256), 0, stream>>>(W2, B2, NF, EI, DI, W1, B1, WT,
                                            w2c, ht2, tmo, out, nz4);
  if (fast) {
    k2_gemm<0><<<dim3(512),  dim3(256), 0, stream>>>(w2c, ht2, tmo, EI, fp, out);
    k4_reduce <<<dim3(1024), dim3(256), 0, stream>>>(fp, EI, out);
  } else {
    k2_gemm<1><<<dim3(512),  dim3(256), 0, stream>>>(w2c, ht2, tmo, EI, fp, out);
  }
  k3_silu<<<dim3(1024), dim3(256), 0, stream>>>(out, nz4);
}